// Round 4
// baseline (247.308 us; speedup 1.0000x reference)
//
#include <hip/hip_runtime.h>

#define D_CH   1024
#define L_SEQ  8192
#define W_N    3.8349519697141029e-4f   /* 2*pi/16384 */
#define W128A  4.90873852123405e-2f     /* 2*pi/128 */

#ifndef __has_builtin
#define __has_builtin(x) 0
#endif

// ---------------- bf16 pack/unpack --------------------------------------
__device__ __forceinline__ unsigned f2bf(float v){
  union { float f; unsigned u; } x; x.f = v;
  unsigned r = x.u + 0x7fffu + ((x.u >> 16) & 1u);
  return r >> 16;
}
__device__ __forceinline__ float bf2f(unsigned v){
  union { float f; unsigned u; } x; x.u = v << 16;
  return x.f;
}
#if __has_builtin(__builtin_amdgcn_cvt_pk_bf16_f32)
__device__ __forceinline__ unsigned packc(float r, float i){
  auto h = __builtin_amdgcn_cvt_pk_bf16_f32(r, i);   // low = r, high = i (RNE)
  unsigned u; __builtin_memcpy(&u, &h, 4); return u;
}
#else
__device__ __forceinline__ unsigned packc(float r, float i){
  return f2bf(r) | (f2bf(i) << 16);
}
#endif
__device__ __forceinline__ float2 upk(unsigned u){
  return make_float2(bf2f(u & 0xffffu), bf2f(u >> 16));
}
__device__ __forceinline__ float2 cmul(float2 a, float2 b){
  return make_float2(a.x*b.x - a.y*b.y, a.x*b.y + a.y*b.x);
}

__device__ __host__ constexpr int bitrev4(int j){
  return ((j&1)<<3)|((j&2)<<1)|((j&4)>>1)|((j&8)>>3);
}
__device__ __host__ constexpr int bitrev3(int j){
  return ((j&1)<<2)|(j&2)|((j&4)>>2);
}

// 16-pt DIF DFT, natural in; slot j holds X[bitrev4(j)].
template<int SGN>
__device__ __forceinline__ void dft16(float2* x){
  const float TC[8] = {1.f, 0.9238795325f, 0.7071067812f, 0.3826834324f,
                       0.f, -0.3826834324f, -0.7071067812f, -0.9238795325f};
  const float TS[8] = {0.f, -0.3826834324f, -0.7071067812f, -0.9238795325f,
                       -1.f, -0.9238795325f, -0.7071067812f, -0.3826834324f};
#pragma unroll
  for (int len = 16; len >= 2; len >>= 1){
    const int half = len >> 1, tstep = 16 / len;
#pragma unroll
    for (int st = 0; st < 16; st += len){
#pragma unroll
      for (int j = 0; j < half; j++){
        const float wr = TC[j*tstep];
        const float wi = (SGN > 0) ? TS[j*tstep] : -TS[j*tstep];
        const int a = st + j, b = a + half;
        const float ur = x[a].x, ui = x[a].y;
        const float vr = x[b].x, vi = x[b].y;
        x[a].x = ur + vr; x[a].y = ui + vi;
        const float dr = ur - vr, di = ui - vi;
        x[b].x = dr*wr - di*wi;
        x[b].y = dr*wi + di*wr;
      }
    }
  }
}

// 8-pt DIF DFT, natural in; slot j holds X[bitrev3(j)].
template<int SGN>
__device__ __forceinline__ void dft8(float2* x){
  const float TC[4] = {1.f, 0.7071067812f, 0.f, -0.7071067812f};
  const float TS[4] = {0.f, -0.7071067812f, -1.f, -0.7071067812f};
#pragma unroll
  for (int len = 8; len >= 2; len >>= 1){
    const int half = len >> 1, tstep = 8 / len;
#pragma unroll
    for (int st = 0; st < 8; st += len){
#pragma unroll
      for (int j = 0; j < half; j++){
        const float wr = TC[j*tstep];
        const float wi = (SGN > 0) ? TS[j*tstep] : -TS[j*tstep];
        const int a = st + j, b = a + half;
        const float ur = x[a].x, ui = x[a].y;
        const float vr = x[b].x, vi = x[b].y;
        x[a].x = ur + vr; x[a].y = ui + vi;
        const float dr = ur - vr, di = ui - vi;
        x[b].x = dr*wr - di*wi;
        x[b].y = dr*wi + di*wr;
      }
    }
  }
}

// 8-pt DIT DFT: slot t holds in[bitrev3(t)], natural output
// out[u] = sum_r in[r] e^{-i SGN 2pi r u / 8}.
template<int SGN>
__device__ __forceinline__ void dft8_dit(float2* x){
  const float TC[4] = {1.f, 0.7071067812f, 0.f, -0.7071067812f};
  const float TS[4] = {0.f, -0.7071067812f, -1.f, -0.7071067812f};
#pragma unroll
  for (int len = 2; len <= 8; len <<= 1){
    const int half = len >> 1, tstep = 8 / len;
#pragma unroll
    for (int st = 0; st < 8; st += len){
#pragma unroll
      for (int j = 0; j < half; j++){
        const float wr = TC[j*tstep];
        const float wi = (SGN > 0) ? TS[j*tstep] : -TS[j*tstep];
        const int a = st + j, b = a + half;
        const float br = x[b].x, bi = x[b].y;
        const float tr = br*wr - bi*wi, ti = br*wi + bi*wr;
        const float ar = x[a].x, ai = x[a].y;
        x[a].x = ar + tr; x[a].y = ai + ti;
        x[b].x = ar - tr; x[b].y = ai - ti;
      }
    }
  }
}

// 128-pt DFT across 8 p-threads (p = tid>>6) x 64 channels (lane).
// Entry: v[q] = f[p + 8q]. Exit: v[c*8+t] = F[(2p+c) + 16*bitrev3(t)].
// Twiddles by chained cmul off one sincos base. 32 KiB LDS, 3 barriers.
// Caller must __syncthreads() before reusing lds afterwards.
template<int SGN>
__device__ __forceinline__ void fft128(float2* v, float2* lds, int lane, int p){
  dft16<SGN>(v);                         // slot -> s = bitrev4(slot)
  float sn, cs;
  __sincosf(-(float)SGN * W128A * (float)p, &sn, &cs);
  const float2 base  = make_float2(cs, sn);       // w128^{p}
  const float2 base2 = cmul(base, base);          // w128^{2p}
  // ---- phase 0: even s = 2r ----
  float2 w = make_float2(1.f, 0.f);
#pragma unroll
  for (int r = 0; r < 8; r++){
    const int slot = bitrev3(r);         // bitrev3 is an involution
    lds[(p*8 + r)*64 + lane] = cmul(v[slot], w);
    w = cmul(w, base2);
  }
  __syncthreads();
  float2 t8[8];
#pragma unroll
  for (int pp = 0; pp < 8; pp++) t8[pp] = lds[(pp*8 + p)*64 + lane]; // s=2p
  dft8<SGN>(t8);
#pragma unroll
  for (int t = 0; t < 8; t++) v[t] = t8[t];
  __syncthreads();                       // reads done before phase-1 stores
  // ---- phase 1: odd s = 2r+1 ----
  w = base;
#pragma unroll
  for (int r = 0; r < 8; r++){
    const int slot = 8 + bitrev3(r);
    lds[(p*8 + r)*64 + lane] = cmul(v[slot], w);
    w = cmul(w, base2);
  }
  __syncthreads();
#pragma unroll
  for (int pp = 0; pp < 8; pp++) t8[pp] = lds[(pp*8 + p)*64 + lane]; // s=2p+1
  dft8<SGN>(t8);
#pragma unroll
  for (int t = 0; t < 8; t++) v[8 + t] = t8[t];
}

// Reverse-order 128-pt DFT: consumes fft128's EXIT order, emits natural.
// Entry: v[c*8+t] = Y[(2p+c) + 16*bitrev3(t)].
// Exit:  v[slot]  = y[m2 = p + 8*bitrev4(slot)],
//        y[m2] = sum_k2 Y[k2] e^{-i SGN 2pi k2 m2 / 128}.
// In-thread dft8 over r, twiddle chain, one 32KiB transpose, in-thread dft16.
template<int SGN>
__device__ __forceinline__ void fft128_rev(float2* v, float2* lds, int lane, int p){
  float2 B[16];
#pragma unroll
  for (int c = 0; c < 2; c++){
    float2 t8[8];
#pragma unroll
    for (int t = 0; t < 8; t++) t8[t] = v[c*8 + t];
    dft8_dit<SGN>(t8);                   // natural u
    const int s = 2*p + c;
    float sn, cs;
    __sincosf(-(float)SGN * W128A * (float)s, &sn, &cs);
    const float2 bs = make_float2(cs, sn);          // w128^{s}
    float2 w = make_float2(1.f, 0.f);
#pragma unroll
    for (int u = 0; u < 8; u++){
      B[c*8 + u] = cmul(t8[u], w);       // B'[s,u] = B[s,u] * w128^{s u}
      w = cmul(w, bs);
    }
  }
  // transpose (u,s) in two 32 KiB phases
#pragma unroll
  for (int c = 0; c < 2; c++)
#pragma unroll
    for (int u = 0; u < 4; u++)
      lds[(u*16 + 2*p + c)*64 + lane] = B[c*8 + u];
  __syncthreads();
  float2 g[16];
  if (p < 4){
#pragma unroll
    for (int s = 0; s < 16; s++) g[s] = lds[(p*16 + s)*64 + lane];
  }
  __syncthreads();
#pragma unroll
  for (int c = 0; c < 2; c++)
#pragma unroll
    for (int u = 4; u < 8; u++)
      lds[((u-4)*16 + 2*p + c)*64 + lane] = B[c*8 + u];
  __syncthreads();
  if (p >= 4){
#pragma unroll
    for (int s = 0; s < 16; s++) g[s] = lds[((p-4)*16 + s)*64 + lane];
  }
  dft16<SGN>(g);                         // over s, freq k = bitrev4(slot)
#pragma unroll
  for (int t = 0; t < 16; t++) v[t] = g[t];
}

// ---------------------------------------------------------------------------
// K1: forward step1 over n1 (64 nonzero of 128, zero-padded).
// A[k1,n2] = w16384^{k1 n2} * DFT128_{n1}(z[n2+128 n1]).
// mode 0: z = x[0] + i x[1]; mode 1: h.
// ---------------------------------------------------------------------------
__global__ __launch_bounds__(512, 4)
void k1_step1(const float* __restrict__ x, const float* __restrict__ h,
              unsigned* __restrict__ Az, unsigned* __restrict__ Ah){
  __shared__ float2 lds[4096];
  const int n2 = blockIdx.x, dg = blockIdx.y, mode = blockIdx.z;
  const int lane = threadIdx.x & 63, p = threadIdx.x >> 6;
  const int d = dg*64 + lane;

  float2 v[16];
  if (mode == 0){
    const float* x0 = x;
    const float* x1 = x + (size_t)L_SEQ * D_CH;
#pragma unroll
    for (int q = 0; q < 8; q++){
      const size_t off = (size_t)(n2 + 128*(p + 8*q)) * D_CH + d;
      v[q] = make_float2(x0[off], x1[off]);
    }
  } else {
#pragma unroll
    for (int q = 0; q < 8; q++){
      const size_t off = (size_t)(n2 + 128*(p + 8*q)) * D_CH + d;
      v[q] = make_float2(h[off], 0.0f);
    }
  }
#pragma unroll
  for (int q = 8; q < 16; q++) v[q] = make_float2(0.f, 0.f);

  fft128<1>(v, lds, lane, p);

  // epilogue twiddle w16384^{k1v * n2}, k1v = (2p+c) + 16r, by chain
  float sn, cs;
  __sincosf(-W_N * (float)(2*p*n2), &sn, &cs);
  float2 b0 = make_float2(cs, sn);                 // c=0 base
  __sincosf(-W_N * (float)n2, &sn, &cs);
  const float2 u1 = make_float2(cs, sn);
  float2 b1 = cmul(b0, u1);                        // c=1 base
  __sincosf(-W_N * (float)(16*n2), &sn, &cs);
  const float2 s16 = make_float2(cs, sn);          // step per r

  unsigned* __restrict__ A = mode ? Ah : Az;
#pragma unroll
  for (int r = 0; r < 8; r++){
    const int t = bitrev3(r);
    {
      const int k1v = 2*p + 16*r;
      const float2 a = cmul(v[t], b0);
      A[((size_t)k1v*128 + n2)*D_CH + d] = packc(a.x, a.y);
    }
    {
      const int k1v = 2*p + 1 + 16*r;
      const float2 a = cmul(v[8 + t], b1);
      A[((size_t)k1v*128 + n2)*D_CH + d] = packc(a.x, a.y);
    }
    b0 = cmul(b0, s16);
    b1 = cmul(b1, s16);
  }
}

// ---------------------------------------------------------------------------
// K2 (fused): forward step2 for h (in-register Hspec, never stored) +
// forward step2 for z + pointwise Z*H/16384 + inverse over k2 via fft128_rev,
// in place on A_z: result b[k1,m2] stored at natural m2.
// ---------------------------------------------------------------------------
__global__ __launch_bounds__(512, 4)
void k2_zh(unsigned* __restrict__ Az, const unsigned* __restrict__ Ah){
  __shared__ float2 lds[4096];
  const int k1 = blockIdx.x, dg = blockIdx.y;
  const int lane = threadIdx.x & 63, p = threadIdx.x >> 6;
  const int d = dg*64 + lane;
  const size_t base = (size_t)k1 * 128 * D_CH + d;

  // issue all independent loads up front (MLP)
  unsigned ha[16], za[16];
#pragma unroll
  for (int q = 0; q < 16; q++)
    ha[q] = Ah[base + (size_t)(p + 8*q) * D_CH];
#pragma unroll
  for (int q = 0; q < 16; q++)
    za[q] = Az[base + (size_t)(p + 8*q) * D_CH];

  // ---- H: forward 128-pt over n2, spectrum kept packed in regs ----
  float2 v[16];
#pragma unroll
  for (int q = 0; q < 16; q++) v[q] = upk(ha[q]);
  fft128<1>(v, lds, lane, p);
  unsigned hs[16];
  const float sc = 1.0f / 16384.0f;      // fold ifft scale into Hspec
#pragma unroll
  for (int i = 0; i < 16; i++) hs[i] = packc(v[i].x * sc, v[i].y * sc);
  __syncthreads();                       // lds reads done before z-fft stores

  // ---- Z: forward 128-pt over n2 ----
#pragma unroll
  for (int q = 0; q < 16; q++) v[q] = upk(za[q]);
  fft128<1>(v, lds, lane, p);

  // ---- pointwise multiply (orders match exactly) ----
#pragma unroll
  for (int i = 0; i < 16; i++){
    const float2 hv = upk(hs[i]);
    const float zr = v[i].x, zi = v[i].y;
    v[i] = make_float2(zr*hv.x - zi*hv.y, zr*hv.y + zi*hv.x);
  }

  // ---- inverse 128-pt over k2, directly from spectrum order ----
  __syncthreads();                       // protect fft128's phase-1 lds reads
  fft128_rev<-1>(v, lds, lane, p);       // v[slot] = b[m2 = p + 8*bitrev4(slot)]

#pragma unroll
  for (int t = 0; t < 16; t++){
    const int m2 = p + 8*bitrev4(t);
    const float2 a = v[t];
    Az[base + (size_t)m2 * D_CH] = packc(a.x, a.y);
  }
}

// ---------------------------------------------------------------------------
// K3: inverse step2 over k1 + bias + output write.
// y[0,t,d] = Re(w)+bias, y[1,t,d] = Im(w)+bias, t = m2 + 128*m1, m1 < 64.
// ---------------------------------------------------------------------------
__global__ __launch_bounds__(512, 4)
void k3_inv2(const unsigned* __restrict__ Bz, const float* __restrict__ bias,
             float* __restrict__ out){
  __shared__ float2 lds[4096];
  const int m2 = blockIdx.x, dg = blockIdx.y;
  const int lane = threadIdx.x & 63, p = threadIdx.x >> 6;
  const int d = dg*64 + lane;
  const float bv = bias[d];

  unsigned raw[16];
#pragma unroll
  for (int q = 0; q < 16; q++){
    const int k1 = p + 8*q;
    raw[q] = Bz[((size_t)k1*128 + m2) * D_CH + d];
  }
  // prologue twiddle e^{+2pi i m2 k1 / 16384}, k1 = p + 8q, by chain
  float sn, cs;
  __sincosf(W_N * (float)(m2*p), &sn, &cs);
  float2 b = make_float2(cs, sn);
  __sincosf(W_N * (float)(8*m2), &sn, &cs);
  const float2 st8 = make_float2(cs, sn);
  float2 v[16];
#pragma unroll
  for (int q = 0; q < 16; q++){
    v[q] = cmul(upk(raw[q]), b);
    b = cmul(b, st8);
  }

  fft128<-1>(v, lds, lane, p);           // v[c*8+t] = w[m1=(2p+c)+16*bitrev3(t)]

#pragma unroll
  for (int c = 0; c < 2; c++){
#pragma unroll
    for (int t = 0; t < 8; t += 2){      // t even <=> bitrev3(t)<4 <=> m1 < 64
      const int m1 = (2*p + c) + 16*bitrev3(t);
      const int tseq = m2 + 128*m1;
      const float2 a = v[c*8 + t];
      out[(size_t)tseq * D_CH + d]            = a.x + bv;
      out[(size_t)(L_SEQ + tseq) * D_CH + d]  = a.y + bv;
    }
  }
}

// ---------------------------------------------------------------------------
extern "C" void kernel_launch(void* const* d_in, const int* in_sizes, int n_in,
                              void* d_out, int out_size, void* d_ws, size_t ws_size,
                              hipStream_t stream){
  (void)in_sizes; (void)n_in; (void)out_size;
  const float* x    = (const float*)d_in[0];
  const float* h    = (const float*)d_in[1];
  const float* bias = (const float*)d_in[2];
  float* out = (float*)d_out;

  const size_t REGION = (size_t)128 * 128 * D_CH * sizeof(unsigned); // 64 MiB
  unsigned *r1, *r2;
  if (ws_size >= 2 * REGION){
    r1 = (unsigned*)d_ws;                       // A_z -> b
    r2 = (unsigned*)((char*)d_ws + REGION);     // A_h
  } else {
    r1 = (unsigned*)d_out;  // safe: K3 reads each r1 cell before its stores
    r2 = (unsigned*)d_ws;   // requires ws_size >= 64 MiB
  }

  const dim3 blk(512, 1, 1);
  hipLaunchKernelGGL(k1_step1, dim3(128,16,2), blk, 0, stream, x, h, r1, r2);
  hipLaunchKernelGGL(k2_zh,    dim3(128,16,1), blk, 0, stream, r1, r2);
  hipLaunchKernelGGL(k3_inv2,  dim3(128,16,1), blk, 0, stream, r1, bias, out);
}